// Round 1
// baseline (268.361 us; speedup 1.0000x reference)
//
#include <hip/hip_runtime.h>
#include <hip/hip_bf16.h>

// ---------------------------------------------------------------------------
// Qwen3 attention block on MI355X, bf16 MFMA pipeline:
//   cvt(fp32->bf16) -> gemm_bt(QKV) -> norm+rope+cache -> flash attn -> gemm_bt(O)
// Shapes: B=2 S=1024 HID=2048 H=32 KV=4 D=128; qkv row = 5120 (q 0..4096, k ..4608, v ..5120)
// ---------------------------------------------------------------------------

typedef __attribute__((ext_vector_type(8))) __bf16 bf16x8;
typedef __attribute__((ext_vector_type(4))) __bf16 bf16x4;
typedef __attribute__((ext_vector_type(4))) float f32x4;

// ---------------- fp32 -> bf16 convert (grid-stride, float4) ----------------
__global__ __launch_bounds__(256) void cvt_f32_bf16(const float* __restrict__ src,
                                                    __bf16* __restrict__ dst, int n4) {
    int i = blockIdx.x * 256 + threadIdx.x;
    int stride = gridDim.x * 256;
    for (; i < n4; i += stride) {
        float4 v = reinterpret_cast<const float4*>(src)[i];
        bf16x4 o = {(__bf16)v.x, (__bf16)v.y, (__bf16)v.z, (__bf16)v.w};
        reinterpret_cast<bf16x4*>(dst)[i] = o;
    }
}

// ---------------- GEMM: C[m][n] = sum_k A[m][k]*B[n][k]  (both row-major, B "transposed" input)
// 128x128 tile, BK=64, 256 threads (2x2 waves of 64x64), 16x16x32 bf16 MFMA.
// LDS stride padded to 72 elems: fragment ds_read_b128 base banks spread uniformly.
template <int OUT_BF16>
__global__ __launch_bounds__(256) void gemm_bt(const __bf16* __restrict__ A,
                                               const __bf16* __restrict__ B,
                                               void* __restrict__ C,
                                               const int M, const int N, const int K) {
    constexpr int LDT = 72;
    __shared__ __bf16 As[128 * LDT];
    __shared__ __bf16 Bs[128 * LDT];
    const int tid = threadIdx.x;
    const int lane = tid & 63;
    const int wave = tid >> 6;
    const int bn = blockIdx.x, bm = blockIdx.y;
    const int brow = bm * 128, bcol = bn * 128;
    const int wr = wave >> 1, wc = wave & 1;
    const int lrow = lane & 15, lkg = lane >> 4;
    const int srow = tid >> 3;          // 0..31 staging row base
    const int scol = (tid & 7) * 8;     // 0..56 staging col (8 bf16 per uint4)
    f32x4 acc[4][4] = {};

    for (int k0 = 0; k0 < K; k0 += 64) {
        __syncthreads();
#pragma unroll
        for (int r = 0; r < 4; ++r) {
            const int row = srow + r * 32;
            *reinterpret_cast<uint4*>(&As[row * LDT + scol]) =
                *reinterpret_cast<const uint4*>(&A[(size_t)(brow + row) * K + k0 + scol]);
            *reinterpret_cast<uint4*>(&Bs[row * LDT + scol]) =
                *reinterpret_cast<const uint4*>(&B[(size_t)(bcol + row) * K + k0 + scol]);
        }
        __syncthreads();
#pragma unroll
        for (int kk = 0; kk < 2; ++kk) {
            bf16x8 a[4], b[4];
#pragma unroll
            for (int m = 0; m < 4; ++m)
                a[m] = *reinterpret_cast<const bf16x8*>(&As[(wr * 64 + m * 16 + lrow) * LDT + kk * 32 + lkg * 8]);
#pragma unroll
            for (int n = 0; n < 4; ++n)
                b[n] = *reinterpret_cast<const bf16x8*>(&Bs[(wc * 64 + n * 16 + lrow) * LDT + kk * 32 + lkg * 8]);
#pragma unroll
            for (int m = 0; m < 4; ++m)
#pragma unroll
                for (int n = 0; n < 4; ++n)
                    acc[m][n] = __builtin_amdgcn_mfma_f32_16x16x32_bf16(a[m], b[n], acc[m][n], 0, 0, 0);
        }
    }
    // epilogue: D[row=(lane>>4)*4+j][col=lane&15] per 16x16 fragment
#pragma unroll
    for (int m = 0; m < 4; ++m)
#pragma unroll
        for (int n = 0; n < 4; ++n)
#pragma unroll
            for (int j = 0; j < 4; ++j) {
                const size_t r = brow + wr * 64 + m * 16 + lkg * 4 + j;
                const size_t c = bcol + wc * 64 + n * 16 + lrow;
                if (OUT_BF16)
                    ((__bf16*)C)[r * N + c] = (__bf16)acc[m][n][j];
                else
                    ((float*)C)[r * N + c] = acc[m][n][j];
            }
}

// ---------------- per-token RMSNorm + RoPE + paged cache scatter ----------------
// One block per token (256 thr = 4 waves). Lane l owns dims (l, l+64) of each head.
__global__ __launch_bounds__(256) void norm_rope_cache(
    __bf16* __restrict__ qkv, const float* __restrict__ cosT, const float* __restrict__ sinT,
    const float* __restrict__ qw, const float* __restrict__ kw,
    const int* __restrict__ ptab, float* __restrict__ cacheK, float* __restrict__ cacheV) {
    const int t = blockIdx.x;
    const int b = t >> 10, s = t & 1023;
    const int wave = threadIdx.x >> 6, lane = threadIdx.x & 63;
    __bf16* row = qkv + (size_t)t * 5120;
    const float c = cosT[s * 128 + lane];   // cos[d+64] == cos[d]
    const float sn = sinT[s * 128 + lane];
    const int page = ptab[b * 32 + (s >> 5)];
    const int so = s & 31;
    const float wq0 = qw[lane], wq1 = qw[lane + 64];
    // 8 q heads per wave
#pragma unroll
    for (int i = 0; i < 8; ++i) {
        const int h = wave * 8 + i;
        float x0 = (float)row[h * 128 + lane];
        float x1 = (float)row[h * 128 + 64 + lane];
        float ss = x0 * x0 + x1 * x1;
        for (int off = 32; off; off >>= 1) ss += __shfl_xor(ss, off);
        const float rs = rsqrtf(ss * (1.0f / 128.0f) + 1e-6f);
        const float y0 = x0 * rs * wq0, y1 = x1 * rs * wq1;
        row[h * 128 + lane]      = (__bf16)(y0 * c - y1 * sn);
        row[h * 128 + 64 + lane] = (__bf16)(y1 * c + y0 * sn);
    }
    // k head (one per wave) + v cache copy
    {
        const int h = wave;  // 4 kv heads, 4 waves
        float x0 = (float)row[4096 + h * 128 + lane];
        float x1 = (float)row[4096 + h * 128 + 64 + lane];
        float ss = x0 * x0 + x1 * x1;
        for (int off = 32; off; off >>= 1) ss += __shfl_xor(ss, off);
        const float rs = rsqrtf(ss * (1.0f / 128.0f) + 1e-6f);
        const float y0 = x0 * rs * kw[lane], y1 = x1 * rs * kw[lane + 64];
        const float o0 = y0 * c - y1 * sn, o1 = y1 * c + y0 * sn;
        row[4096 + h * 128 + lane]      = (__bf16)o0;
        row[4096 + h * 128 + 64 + lane] = (__bf16)o1;
        float* ck = cacheK + (((size_t)page * 4 + h) * 32 + so) * 128;
        ck[lane] = o0; ck[lane + 64] = o1;
        const float v0 = (float)row[4608 + h * 128 + lane];
        const float v1 = (float)row[4608 + h * 128 + 64 + lane];
        float* cv = cacheV + (((size_t)page * 4 + h) * 32 + so) * 128;
        cv[lane] = v0; cv[lane + 64] = v1;
    }
}

// ---------------- flash attention, causal GQA ----------------
// grid (qblk=16, h=32, b=2), 256 thr = 4 waves x 16 q-rows; KV tile = 32.
// Swapped QK^T: St[kv][q] = mfma(K_tile, Q^T) so each lane owns one q column.
__global__ __launch_bounds__(256) void attn_fwd(const __bf16* __restrict__ qkv,
                                                __bf16* __restrict__ out) {
    constexpr int LKT = 136, LVT = 48, LPT = 40;
    __shared__ __bf16 Ks[32 * LKT];      // [kv][d] padded
    __shared__ __bf16 Vt[128 * LVT];     // [d][kv] padded (transposed)
    __shared__ __bf16 Ps[4 * 16 * LPT];  // per-wave P tile [q][kv]
    const int qb = blockIdx.x, h = blockIdx.y, b = blockIdx.z;
    const int tid = threadIdx.x, wave = tid >> 6, lane = tid & 63;
    const int lrow = lane & 15, lkg = lane >> 4;
    const size_t base = (size_t)b * 1024 * 5120;
    const int kofs = 4096 + (h >> 3) * 128, vofs = 4608 + (h >> 3) * 128;
    const int wbase = qb * 64 + wave * 16;

    // Q fragments in registers (B-operand layout): aq[kc][i] = Q[lrow][kc*32+lkg*8+i]
    bf16x8 aq[4];
#pragma unroll
    for (int kc = 0; kc < 4; ++kc)
        aq[kc] = *reinterpret_cast<const bf16x8*>(
            &qkv[base + (size_t)(wbase + lrow) * 5120 + h * 128 + kc * 32 + lkg * 8]);

    f32x4 acc[8] = {};           // O[q=lkg*4+j][d=f*16+lrow]
    float m_i = -1e30f, l_i = 0.f;
    const int nt = 2 * qb + 2;
    const int krow = tid >> 4, kcol8 = (tid & 15) * 8;  // K staging
    const int vrow = tid & 31, vc16 = tid >> 5;         // V staging (transposed scatter)

    for (int t = 0; t < nt; ++t) {
        const int kv0 = t * 32;
        __syncthreads();
#pragma unroll
        for (int r = 0; r < 2; ++r) {
            const int row = krow + r * 16;
            *reinterpret_cast<uint4*>(&Ks[row * LKT + kcol8]) =
                *reinterpret_cast<const uint4*>(&qkv[base + (size_t)(kv0 + row) * 5120 + kofs + kcol8]);
        }
#pragma unroll
        for (int r = 0; r < 2; ++r) {
            const int c16 = vc16 + r * 8;
            uint4 vv = *reinterpret_cast<const uint4*>(&qkv[base + (size_t)(kv0 + vrow) * 5120 + vofs + c16 * 8]);
            const __bf16* pv = reinterpret_cast<const __bf16*>(&vv);
#pragma unroll
            for (int j = 0; j < 8; ++j) Vt[(c16 * 8 + j) * LVT + vrow] = pv[j];
        }
        __syncthreads();
        if (kv0 > wbase + 15) continue;  // fully-masked tile for this wave (barrier counts stay aligned)

        // QK^T -> St[kv][q]
        f32x4 st[2] = {};
#pragma unroll
        for (int kc = 0; kc < 4; ++kc) {
            bf16x8 ak0 = *reinterpret_cast<const bf16x8*>(&Ks[(lrow) * LKT + kc * 32 + lkg * 8]);
            bf16x8 ak1 = *reinterpret_cast<const bf16x8*>(&Ks[(16 + lrow) * LKT + kc * 32 + lkg * 8]);
            st[0] = __builtin_amdgcn_mfma_f32_16x16x32_bf16(ak0, aq[kc], st[0], 0, 0, 0);
            st[1] = __builtin_amdgcn_mfma_f32_16x16x32_bf16(ak1, aq[kc], st[1], 0, 0, 0);
        }
        // scale + causal mask + online softmax (lane's q col = wbase+lrow)
        const int qpos = wbase + lrow;
        float sv[8];
        float pmax = -1e30f;
#pragma unroll
        for (int f = 0; f < 2; ++f)
#pragma unroll
            for (int j = 0; j < 4; ++j) {
                const int kvpos = kv0 + f * 16 + lkg * 4 + j;
                float x = st[f][j] * 0.08838834764831845f;
                if (kvpos > qpos) x = -1e30f;
                sv[f * 4 + j] = x;
                pmax = fmaxf(pmax, x);
            }
        pmax = fmaxf(pmax, __shfl_xor(pmax, 16));
        pmax = fmaxf(pmax, __shfl_xor(pmax, 32));
        const float m_new = fmaxf(m_i, pmax);
        const float sf = __expf(m_i - m_new);
        float ladd = 0.f;
#pragma unroll
        for (int f = 0; f < 2; ++f)
#pragma unroll
            for (int j = 0; j < 4; ++j) {
                const float p = __expf(sv[f * 4 + j] - m_new);
                ladd += p;
                Ps[(wave * 16 + lrow) * LPT + f * 16 + lkg * 4 + j] = (__bf16)p;
            }
        ladd += __shfl_xor(ladd, 16);
        ladd += __shfl_xor(ladd, 32);
        l_i = l_i * sf + ladd;
        m_i = m_new;
        // rescale O: factor for q row (lkg*4+j) lives in lane (lkg*4+j)
        float sfj[4];
#pragma unroll
        for (int j = 0; j < 4; ++j) sfj[j] = __shfl(sf, lkg * 4 + j);
#pragma unroll
        for (int f = 0; f < 8; ++f)
#pragma unroll
            for (int j = 0; j < 4; ++j) acc[f][j] *= sfj[j];
        // PV: A = P[q][kv] (from LDS), B = V[kv][d] (transposed LDS -> b128 reads)
        bf16x8 ap = *reinterpret_cast<const bf16x8*>(&Ps[(wave * 16 + lrow) * LPT + lkg * 8]);
#pragma unroll
        for (int f = 0; f < 8; ++f) {
            bf16x8 bv = *reinterpret_cast<const bf16x8*>(&Vt[(f * 16 + lrow) * LVT + lkg * 8]);
            acc[f] = __builtin_amdgcn_mfma_f32_16x16x32_bf16(ap, bv, acc[f], 0, 0, 0);
        }
    }
    // epilogue: divide by l, write bf16
    float linv[4];
#pragma unroll
    for (int j = 0; j < 4; ++j) linv[j] = 1.0f / __shfl(l_i, lkg * 4 + j);
#pragma unroll
    for (int f = 0; f < 8; ++f)
#pragma unroll
        for (int j = 0; j < 4; ++j) {
            const size_t r = (size_t)b * 1024 + wbase + lkg * 4 + j;
            out[r * 4096 + h * 128 + f * 16 + lrow] = (__bf16)(acc[f][j] * linv[j]);
        }
}

// ---------------------------------------------------------------------------
extern "C" void kernel_launch(void* const* d_in, const int* in_sizes, int n_in,
                              void* d_out, int out_size, void* d_ws, size_t ws_size,
                              hipStream_t stream) {
    const float* hidden = (const float*)d_in[0];
    const float* wq = (const float*)d_in[1];
    const float* wk = (const float*)d_in[2];
    const float* wv = (const float*)d_in[3];
    const float* wo = (const float*)d_in[4];
    const float* qnw = (const float*)d_in[5];
    const float* knw = (const float*)d_in[6];
    const float* cosT = (const float*)d_in[7];
    const float* sinT = (const float*)d_in[8];
    const int* ptab = (const int*)d_in[9];

    float* outp = (float*)d_out;                 // (2,1024,2048)
    float* cacheK = outp + 4194304;              // (128,4,32,128)
    float* cacheV = cacheK + 2097152;

    // workspace layout (bytes): [hbf 0..8M][w1bf 8M..28M][wobf 28M..44M][qkvbf 44M..64M]
    // attnbf overlays [0..16M] (hbf+w1bf dead by then). Total 64MiB-ish.
    char* ws = (char*)d_ws;
    __bf16* hbf    = (__bf16*)ws;                       // 2048x2048
    __bf16* w1bf   = (__bf16*)(ws + 8388608);           // 5120x2048 (wq|wk|wv)
    __bf16* wobf   = (__bf16*)(ws + 29360128);          // 2048x4096
    __bf16* qkvbf  = (__bf16*)(ws + 46137344);          // 2048x5120
    __bf16* attnbf = (__bf16*)ws;                       // 2048x4096 (overlay)

    cvt_f32_bf16<<<2048, 256, 0, stream>>>(hidden, hbf, 2048 * 2048 / 4);
    cvt_f32_bf16<<<2048, 256, 0, stream>>>(wq, w1bf, 4096 * 2048 / 4);
    cvt_f32_bf16<<<512, 256, 0, stream>>>(wk, w1bf + (size_t)4096 * 2048, 512 * 2048 / 4);
    cvt_f32_bf16<<<512, 256, 0, stream>>>(wv, w1bf + (size_t)4608 * 2048, 512 * 2048 / 4);
    cvt_f32_bf16<<<2048, 256, 0, stream>>>(wo, wobf, 2048 * 4096 / 4);

    // QKV projection: (2048x2048) @ (5120x2048)^T -> qkvbf bf16
    gemm_bt<1><<<dim3(40, 16), 256, 0, stream>>>(hbf, w1bf, qkvbf, 2048, 5120, 2048);

    // zero both caches (64 of 128 pages stay zero), then scatter used pages
    hipMemsetAsync(cacheK, 0, (size_t)4194304 * 4, stream);
    norm_rope_cache<<<2048, 256, 0, stream>>>(qkvbf, cosT, sinT, qnw, knw, ptab, cacheK, cacheV);

    attn_fwd<<<dim3(16, 32, 2), 256, 0, stream>>>(qkvbf, attnbf);

    // out projection: (2048x4096) @ (2048x4096)^T -> fp32 d_out
    gemm_bt<0><<<dim3(16, 16), 256, 0, stream>>>(attnbf, wobf, outp, 2048, 2048, 4096);
}